// Round 1
// baseline (962.452 us; speedup 1.0000x reference)
//
#include <hip/hip_runtime.h>

#define BB 2
#define CC 64
#define HH 128
#define WW 128
#define HWN (HH*WW)          // 16384 = 2^14
#define CHW (CC*HWN)         // 2^20

// Stage 1: osum = BN(bias(dw1x15(x))) + BN(bias(dw15x1(x))) + BN(bias(dw3x3(x)))
__global__ void osum_kernel(const float* __restrict__ x,
    const float* __restrict__ w1, const float* __restrict__ b1, const float* __restrict__ s1, const float* __restrict__ g1,
    const float* __restrict__ w2, const float* __restrict__ b2, const float* __restrict__ s2, const float* __restrict__ g2,
    const float* __restrict__ w3, const float* __restrict__ b3, const float* __restrict__ s3, const float* __restrict__ g3,
    float* __restrict__ osum)
{
    int idx = blockIdx.x * blockDim.x + threadIdx.x;   // < B*C*H*W = 2^21
    int w = idx & (WW - 1);
    int h = (idx >> 7) & (HH - 1);
    int c = (idx >> 14) & (CC - 1);
    const float* xp = x + (size_t)(idx >> 14) * HWN;   // (b*C + c) plane

    float a1 = 0.f;
    #pragma unroll
    for (int k = 0; k < 15; ++k) {
        int ww_ = w + k - 7;
        if (ww_ >= 0 && ww_ < WW) a1 += xp[h * WW + ww_] * w1[c * 15 + k];
    }
    float o1 = (a1 + b1[c]) * s1[c] + g1[c];

    float a2 = 0.f;
    #pragma unroll
    for (int k = 0; k < 15; ++k) {
        int hh_ = h + k - 7;
        if (hh_ >= 0 && hh_ < HH) a2 += xp[hh_ * WW + w] * w2[c * 15 + k];
    }
    float o2 = (a2 + b2[c]) * s2[c] + g2[c];

    float a3 = 0.f;
    #pragma unroll
    for (int kh = 0; kh < 3; ++kh) {
        int hh_ = h + kh - 1;
        if (hh_ < 0 || hh_ >= HH) continue;
        #pragma unroll
        for (int kw = 0; kw < 3; ++kw) {
            int ww_ = w + kw - 1;
            if (ww_ >= 0 && ww_ < WW) a3 += xp[hh_ * WW + ww_] * w3[c * 9 + kh * 3 + kw];
        }
    }
    float o3 = (a3 + b3[c]) * s3[c] + g3[c];

    osum[idx] = o1 + o2 + o3;
}

// Stage 2: off[b,j,h,w] = BN(bias(1x1conv(osum, bal_w)))   j in [0,18)
__global__ void off_kernel(const float* __restrict__ osum,
    const float* __restrict__ balw, const float* __restrict__ balb,
    const float* __restrict__ s4, const float* __restrict__ g4,
    float* __restrict__ off)
{
    int idx = blockIdx.x * blockDim.x + threadIdx.x;   // < B*18*HW = 589824
    int hw = idx & (HWN - 1);
    int bj = idx >> 14;
    int j = bj % 18;
    int b = bj / 18;
    const float* op = osum + (size_t)b * CHW + hw;
    const float* wp = balw + j * CC;
    float acc = 0.f;
    #pragma unroll 8
    for (int c = 0; c < CC; ++c) acc += op[(size_t)c << 14] * wp[c];
    off[idx] = (acc + balb[j]) * s4[j] + g4[j];
}

// Stage 3: out_pre[b,c,h,w] = sum_{d in 2..5} sum_{k in 0..8} bilinear(x[b,c], py,px) * dw_d[c,k]
__global__ void deform_kernel(const float* __restrict__ x,
    const float* __restrict__ off,
    const float* __restrict__ dw2, const float* __restrict__ dw3,
    const float* __restrict__ dw4, const float* __restrict__ dw5,
    float* __restrict__ outp)
{
    int idx = blockIdx.x * blockDim.x + threadIdx.x;   // < 2^21
    int w = idx & (WW - 1);
    int h = (idx >> 7) & (HH - 1);
    int c = (idx >> 14) & (CC - 1);
    int b = idx >> 20;
    const float* xp = x + (size_t)(idx >> 14) * HWN;
    const float* offp = off + (size_t)b * (18 * HWN) + (h * WW + w);

    float oy[9], ox[9];
    #pragma unroll
    for (int k = 0; k < 9; ++k) {
        oy[k] = offp[(size_t)(2 * k) << 14];
        ox[k] = offp[(size_t)(2 * k + 1) << 14];
    }

    const float* dwp[4] = { dw2 + c * 9, dw3 + c * 9, dw4 + c * 9, dw5 + c * 9 };

    float acc = 0.f;
    #pragma unroll
    for (int di = 0; di < 4; ++di) {
        float d = (float)(di + 2);
        const float* dw = dwp[di];
        #pragma unroll
        for (int k = 0; k < 9; ++k) {
            float ky = (float)(k / 3 - 1);
            float kx = (float)(k % 3 - 1);
            float py = oy[k] + (float)h + d * ky;
            float px = ox[k] + (float)w + d * kx;
            float y0f = floorf(py);
            float x0f = floorf(px);
            float wy = py - y0f;
            float wx = px - x0f;
            int y0 = (int)y0f;
            int x0 = (int)x0f;
            int y1 = y0 + 1, x1 = x0 + 1;
            bool yv0 = (y0 >= 0) && (y0 < HH);
            bool yv1 = (y1 >= 0) && (y1 < HH);
            bool xv0 = (x0 >= 0) && (x0 < WW);
            bool xv1 = (x1 >= 0) && (x1 < WW);
            int y0c = min(max(y0, 0), HH - 1);
            int y1c = min(max(y1, 0), HH - 1);
            int x0c = min(max(x0, 0), WW - 1);
            int x1c = min(max(x1, 0), WW - 1);
            float v00 = (yv0 && xv0) ? xp[y0c * WW + x0c] : 0.f;
            float v01 = (yv0 && xv1) ? xp[y0c * WW + x1c] : 0.f;
            float v10 = (yv1 && xv0) ? xp[y1c * WW + x0c] : 0.f;
            float v11 = (yv1 && xv1) ? xp[y1c * WW + x1c] : 0.f;
            float s = v00 * (1.f - wy) * (1.f - wx)
                    + v01 * (1.f - wy) * wx
                    + v10 * wy * (1.f - wx)
                    + v11 * wy * wx;
            acc += s * dw[k];
        }
    }
    outp[idx] = acc;
}

// Stage 4: out = (BN(bias(1x1conv(out_pre, fin_w)))) * x
__global__ void final_kernel(const float* __restrict__ pre,
    const float* __restrict__ finw, const float* __restrict__ finb,
    const float* __restrict__ s5, const float* __restrict__ g5,
    const float* __restrict__ x, float* __restrict__ out)
{
    int idx = blockIdx.x * blockDim.x + threadIdx.x;   // < 2^21
    int hw = idx & (HWN - 1);
    int c = (idx >> 14) & (CC - 1);
    int b = idx >> 20;
    const float* pp = pre + ((size_t)b << 20) + hw;
    const float* wp = finw + c * CC;
    float acc = 0.f;
    #pragma unroll 8
    for (int ci = 0; ci < CC; ++ci) acc += pp[(size_t)ci << 14] * wp[ci];
    out[idx] = ((acc + finb[c]) * s5[c] + g5[c]) * x[idx];
}

extern "C" void kernel_launch(void* const* d_in, const int* in_sizes, int n_in,
                              void* d_out, int out_size, void* d_ws, size_t ws_size,
                              hipStream_t stream) {
    const float* x      = (const float*)d_in[0];
    const float* off1_w = (const float*)d_in[1];
    const float* off1_b = (const float*)d_in[2];
    const float* bn1_s  = (const float*)d_in[3];
    const float* bn1_b  = (const float*)d_in[4];
    const float* off2_w = (const float*)d_in[5];
    const float* off2_b = (const float*)d_in[6];
    const float* bn2_s  = (const float*)d_in[7];
    const float* bn2_b  = (const float*)d_in[8];
    const float* off3_w = (const float*)d_in[9];
    const float* off3_b = (const float*)d_in[10];
    const float* bn3_s  = (const float*)d_in[11];
    const float* bn3_b  = (const float*)d_in[12];
    const float* bal_w  = (const float*)d_in[13];
    const float* bal_b  = (const float*)d_in[14];
    const float* bn4_s  = (const float*)d_in[15];
    const float* bn4_b  = (const float*)d_in[16];
    const float* dw2    = (const float*)d_in[17];
    const float* dw3    = (const float*)d_in[18];
    const float* dw4    = (const float*)d_in[19];
    const float* dw5    = (const float*)d_in[20];
    const float* fin_w  = (const float*)d_in[21];
    const float* fin_b  = (const float*)d_in[22];
    const float* bn5_s  = (const float*)d_in[23];
    const float* bn5_b  = (const float*)d_in[24];

    float* ws   = (float*)d_ws;
    float* osum = ws;                                  // 2,097,152 floats
    float* off  = ws + (size_t)BB * CHW;               // 589,824 floats
    float* pre  = off + (size_t)BB * 18 * HWN;         // 2,097,152 floats

    float* out = (float*)d_out;

    const int BLK = 256;
    osum_kernel<<<(BB * CHW) / BLK, BLK, 0, stream>>>(x,
        off1_w, off1_b, bn1_s, bn1_b,
        off2_w, off2_b, bn2_s, bn2_b,
        off3_w, off3_b, bn3_s, bn3_b, osum);
    off_kernel<<<(BB * 18 * HWN) / BLK, BLK, 0, stream>>>(osum, bal_w, bal_b, bn4_s, bn4_b, off);
    deform_kernel<<<(BB * CHW) / BLK, BLK, 0, stream>>>(x, off, dw2, dw3, dw4, dw5, pre);
    final_kernel<<<(BB * CHW) / BLK, BLK, 0, stream>>>(pre, fin_w, fin_b, bn5_s, bn5_b, x, out);
}

// Round 2
// 412.920 us; speedup vs baseline: 2.3308x; 2.3308x over previous
//
#include <hip/hip_runtime.h>

#define BB 2
#define CC 64
#define HH 128
#define WW 128
#define HWN (HH*WW)          // 16384 = 2^14
#define CHW (CC*HWN)         // 2^20

// deform tiling
#define BAND_H 8             // rows of output per block
#define HALO   13            // dilation 5 + |offset| guard 8
#define NBAND  (HH / BAND_H) // 16
#define LDS_ROWS (BAND_H + 2 * HALO)   // 34

// Stage 1: osum = BN(bias(dw1x15(x))) + BN(bias(dw15x1(x))) + BN(bias(dw3x3(x)))
__global__ void osum_kernel(const float* __restrict__ x,
    const float* __restrict__ w1, const float* __restrict__ b1, const float* __restrict__ s1, const float* __restrict__ g1,
    const float* __restrict__ w2, const float* __restrict__ b2, const float* __restrict__ s2, const float* __restrict__ g2,
    const float* __restrict__ w3, const float* __restrict__ b3, const float* __restrict__ s3, const float* __restrict__ g3,
    float* __restrict__ osum)
{
    int idx = blockIdx.x * blockDim.x + threadIdx.x;   // < B*C*H*W = 2^21
    int w = idx & (WW - 1);
    int h = (idx >> 7) & (HH - 1);
    int c = (idx >> 14) & (CC - 1);
    const float* xp = x + (size_t)(idx >> 14) * HWN;   // (b*C + c) plane

    float a1 = 0.f;
    #pragma unroll
    for (int k = 0; k < 15; ++k) {
        int ww_ = w + k - 7;
        if (ww_ >= 0 && ww_ < WW) a1 += xp[h * WW + ww_] * w1[c * 15 + k];
    }
    float o1 = (a1 + b1[c]) * s1[c] + g1[c];

    float a2 = 0.f;
    #pragma unroll
    for (int k = 0; k < 15; ++k) {
        int hh_ = h + k - 7;
        if (hh_ >= 0 && hh_ < HH) a2 += xp[hh_ * WW + w] * w2[c * 15 + k];
    }
    float o2 = (a2 + b2[c]) * s2[c] + g2[c];

    float a3 = 0.f;
    #pragma unroll
    for (int kh = 0; kh < 3; ++kh) {
        int hh_ = h + kh - 1;
        if (hh_ < 0 || hh_ >= HH) continue;
        #pragma unroll
        for (int kw = 0; kw < 3; ++kw) {
            int ww_ = w + kw - 1;
            if (ww_ >= 0 && ww_ < WW) a3 += xp[hh_ * WW + ww_] * w3[c * 9 + kh * 3 + kw];
        }
    }
    float o3 = (a3 + b3[c]) * s3[c] + g3[c];

    osum[idx] = o1 + o2 + o3;
}

// Stage 2: off[b,j,h,w] = BN(bias(1x1conv(osum, bal_w)))   j in [0,18)
__global__ void off_kernel(const float* __restrict__ osum,
    const float* __restrict__ balw, const float* __restrict__ balb,
    const float* __restrict__ s4, const float* __restrict__ g4,
    float* __restrict__ off)
{
    int idx = blockIdx.x * blockDim.x + threadIdx.x;   // < B*18*HW = 589824
    int hw = idx & (HWN - 1);
    int bj = idx >> 14;
    int j = bj % 18;
    int b = bj / 18;
    const float* op = osum + (size_t)b * CHW + hw;
    const float* wp = balw + j * CC;
    float acc = 0.f;
    #pragma unroll 8
    for (int c = 0; c < CC; ++c) acc += op[(size_t)c << 14] * wp[c];
    off[idx] = (acc + balb[j]) * s4[j] + g4[j];
}

// Stage 3: LDS-staged deformable gather.
// Grid: blockIdx.x = ((b*CC + c) << 4) | band.  Block: 256 threads.
// LDS holds rows [r_lo, r_hi) of the (b,c) x-plane (band +/- HALO).
// In-band taps read LDS (conflict-free: bank = col%32, lanes w-contiguous);
// rare |offset|>8 taps fall back to a global read on a per-tap branch.
__global__ __launch_bounds__(256) void deform_kernel(
    const float* __restrict__ x,
    const float* __restrict__ off,
    const float* __restrict__ dw2, const float* __restrict__ dw3,
    const float* __restrict__ dw4, const float* __restrict__ dw5,
    float* __restrict__ outp)
{
    __shared__ float lds[LDS_ROWS * WW];   // 34*128*4 = 17408 B

    int bid  = blockIdx.x;
    int band = bid & (NBAND - 1);
    int bc   = bid >> 4;                   // b*CC + c
    int c    = bc & (CC - 1);
    int b    = bc >> 6;

    const float* xp = x + (size_t)bc * HWN;

    int r_lo = band * BAND_H - HALO; if (r_lo < 0) r_lo = 0;
    int r_hi = band * BAND_H + BAND_H + HALO; if (r_hi > HH) r_hi = HH;
    int n4 = (r_hi - r_lo) * (WW / 4);     // float4 count, <= 1088

    const float4* xv = (const float4*)(xp + r_lo * WW);
    float4* ldsv = (float4*)lds;
    for (int i = threadIdx.x; i < n4; i += 256) ldsv[i] = xv[i];
    __syncthreads();

    // per-channel tap weights (wave-uniform scalar loads)
    float wts[4][9];
    #pragma unroll
    for (int k = 0; k < 9; ++k) {
        wts[0][k] = dw2[c * 9 + k];
        wts[1][k] = dw3[c * 9 + k];
        wts[2][k] = dw4[c * 9 + k];
        wts[3][k] = dw5[c * 9 + k];
    }

    const float* offb = off + (size_t)b * (18 * HWN);

    #pragma unroll
    for (int i = 0; i < (BAND_H * WW) / 256; ++i) {        // 4 pixels/thread
        int p = band * (BAND_H * WW) + i * 256 + threadIdx.x;
        int h = p >> 7;
        int w = p & (WW - 1);

        float oy[9], ox[9];
        #pragma unroll
        for (int k = 0; k < 9; ++k) {
            oy[k] = offb[((size_t)(2 * k) << 14) + p];
            ox[k] = offb[((size_t)(2 * k + 1) << 14) + p];
        }

        float acc = 0.f;
        #pragma unroll
        for (int di = 0; di < 4; ++di) {
            float d = (float)(di + 2);
            #pragma unroll
            for (int k = 0; k < 9; ++k) {
                float ky = (float)(k / 3 - 1);
                float kx = (float)(k % 3 - 1);
                float py = oy[k] + (float)h + d * ky;
                float px = ox[k] + (float)w + d * kx;
                float y0f = floorf(py);
                float x0f = floorf(px);
                float wy = py - y0f;
                float wx = px - x0f;
                int y0 = (int)y0f;
                int x0 = (int)x0f;
                int y1 = y0 + 1, x1 = x0 + 1;
                bool yv0 = (y0 >= 0) && (y0 < HH);
                bool yv1 = (y1 >= 0) && (y1 < HH);
                bool xv0 = (x0 >= 0) && (x0 < WW);
                bool xv1 = (x1 >= 0) && (x1 < WW);
                int y0c = min(max(y0, 0), HH - 1);
                int y1c = min(max(y1, 0), HH - 1);
                int x0c = min(max(x0, 0), WW - 1);
                int x1c = min(max(x1, 0), WW - 1);
                float v00, v01, v10, v11;
                if (y0c >= r_lo && y1c < r_hi) {           // fast path: LDS
                    int r0 = (y0c - r_lo) * WW;
                    int r1 = (y1c - r_lo) * WW;
                    v00 = lds[r0 + x0c];
                    v01 = lds[r0 + x1c];
                    v10 = lds[r1 + x0c];
                    v11 = lds[r1 + x1c];
                } else {                                   // rare fallback
                    v00 = xp[y0c * WW + x0c];
                    v01 = xp[y0c * WW + x1c];
                    v10 = xp[y1c * WW + x0c];
                    v11 = xp[y1c * WW + x1c];
                }
                v00 = (yv0 && xv0) ? v00 : 0.f;
                v01 = (yv0 && xv1) ? v01 : 0.f;
                v10 = (yv1 && xv0) ? v10 : 0.f;
                v11 = (yv1 && xv1) ? v11 : 0.f;
                float s = v00 * (1.f - wy) * (1.f - wx)
                        + v01 * (1.f - wy) * wx
                        + v10 * wy * (1.f - wx)
                        + v11 * wy * wx;
                acc += s * wts[di][k];
            }
        }
        outp[((size_t)bc << 14) + p] = acc;
    }
}

// Stage 4: out = (BN(bias(1x1conv(out_pre, fin_w)))) * x
__global__ void final_kernel(const float* __restrict__ pre,
    const float* __restrict__ finw, const float* __restrict__ finb,
    const float* __restrict__ s5, const float* __restrict__ g5,
    const float* __restrict__ x, float* __restrict__ out)
{
    int idx = blockIdx.x * blockDim.x + threadIdx.x;   // < 2^21
    int hw = idx & (HWN - 1);
    int c = (idx >> 14) & (CC - 1);
    int b = idx >> 20;
    const float* pp = pre + ((size_t)b << 20) + hw;
    const float* wp = finw + c * CC;
    float acc = 0.f;
    #pragma unroll 8
    for (int ci = 0; ci < CC; ++ci) acc += pp[(size_t)ci << 14] * wp[ci];
    out[idx] = ((acc + finb[c]) * s5[c] + g5[c]) * x[idx];
}

extern "C" void kernel_launch(void* const* d_in, const int* in_sizes, int n_in,
                              void* d_out, int out_size, void* d_ws, size_t ws_size,
                              hipStream_t stream) {
    const float* x      = (const float*)d_in[0];
    const float* off1_w = (const float*)d_in[1];
    const float* off1_b = (const float*)d_in[2];
    const float* bn1_s  = (const float*)d_in[3];
    const float* bn1_b  = (const float*)d_in[4];
    const float* off2_w = (const float*)d_in[5];
    const float* off2_b = (const float*)d_in[6];
    const float* bn2_s  = (const float*)d_in[7];
    const float* bn2_b  = (const float*)d_in[8];
    const float* off3_w = (const float*)d_in[9];
    const float* off3_b = (const float*)d_in[10];
    const float* bn3_s  = (const float*)d_in[11];
    const float* bn3_b  = (const float*)d_in[12];
    const float* bal_w  = (const float*)d_in[13];
    const float* bal_b  = (const float*)d_in[14];
    const float* bn4_s  = (const float*)d_in[15];
    const float* bn4_b  = (const float*)d_in[16];
    const float* dw2    = (const float*)d_in[17];
    const float* dw3    = (const float*)d_in[18];
    const float* dw4    = (const float*)d_in[19];
    const float* dw5    = (const float*)d_in[20];
    const float* fin_w  = (const float*)d_in[21];
    const float* fin_b  = (const float*)d_in[22];
    const float* bn5_s  = (const float*)d_in[23];
    const float* bn5_b  = (const float*)d_in[24];

    float* ws   = (float*)d_ws;
    float* osum = ws;                                  // 2,097,152 floats
    float* off  = ws + (size_t)BB * CHW;               // 589,824 floats
    float* pre  = off + (size_t)BB * 18 * HWN;         // 2,097,152 floats

    float* out = (float*)d_out;

    const int BLK = 256;
    osum_kernel<<<(BB * CHW) / BLK, BLK, 0, stream>>>(x,
        off1_w, off1_b, bn1_s, bn1_b,
        off2_w, off2_b, bn2_s, bn2_b,
        off3_w, off3_b, bn3_s, bn3_b, osum);
    off_kernel<<<(BB * 18 * HWN) / BLK, BLK, 0, stream>>>(osum, bal_w, bal_b, bn4_s, bn4_b, off);
    deform_kernel<<<BB * CC * NBAND, 256, 0, stream>>>(x, off, dw2, dw3, dw4, dw5, pre);
    final_kernel<<<(BB * CHW) / BLK, BLK, 0, stream>>>(pre, fin_w, fin_b, bn5_s, bn5_b, x, out);
}

// Round 3
// 329.313 us; speedup vs baseline: 2.9226x; 1.2539x over previous
//
#include <hip/hip_runtime.h>

#define BB 2
#define CC 64
#define HH 128
#define WW 128
#define HWN (HH*WW)          // 16384 = 2^14
#define CHW (CC*HWN)         // 2^20

// deform tiling
#define BAND_H 8             // rows of output per block
#define HALO   13            // dilation 5 + |offset| guard 8
#define NBAND  (HH / BAND_H) // 16
#define LDS_ROWS (BAND_H + 2 * HALO)   // 34
#define CPB 2                // channels per block (geometry shared)
#define PLANE 4356           // LDS_ROWS*128 + 4 pad floats (16B aligned)

// Stage 1: osum = BN(bias(dw1x15(x))) + BN(bias(dw15x1(x))) + BN(bias(dw3x3(x)))
__global__ void osum_kernel(const float* __restrict__ x,
    const float* __restrict__ w1, const float* __restrict__ b1, const float* __restrict__ s1, const float* __restrict__ g1,
    const float* __restrict__ w2, const float* __restrict__ b2, const float* __restrict__ s2, const float* __restrict__ g2,
    const float* __restrict__ w3, const float* __restrict__ b3, const float* __restrict__ s3, const float* __restrict__ g3,
    float* __restrict__ osum)
{
    int idx = blockIdx.x * blockDim.x + threadIdx.x;
    int w = idx & (WW - 1);
    int h = (idx >> 7) & (HH - 1);
    int c = (idx >> 14) & (CC - 1);
    const float* xp = x + (size_t)(idx >> 14) * HWN;

    float a1 = 0.f;
    #pragma unroll
    for (int k = 0; k < 15; ++k) {
        int ww_ = w + k - 7;
        if (ww_ >= 0 && ww_ < WW) a1 += xp[h * WW + ww_] * w1[c * 15 + k];
    }
    float o1 = (a1 + b1[c]) * s1[c] + g1[c];

    float a2 = 0.f;
    #pragma unroll
    for (int k = 0; k < 15; ++k) {
        int hh_ = h + k - 7;
        if (hh_ >= 0 && hh_ < HH) a2 += xp[hh_ * WW + w] * w2[c * 15 + k];
    }
    float o2 = (a2 + b2[c]) * s2[c] + g2[c];

    float a3 = 0.f;
    #pragma unroll
    for (int kh = 0; kh < 3; ++kh) {
        int hh_ = h + kh - 1;
        if (hh_ < 0 || hh_ >= HH) continue;
        #pragma unroll
        for (int kw = 0; kw < 3; ++kw) {
            int ww_ = w + kw - 1;
            if (ww_ >= 0 && ww_ < WW) a3 += xp[hh_ * WW + ww_] * w3[c * 9 + kh * 3 + kw];
        }
    }
    float o3 = (a3 + b3[c]) * s3[c] + g3[c];

    osum[idx] = o1 + o2 + o3;
}

// Stage 2 (LDS-tiled): off[b,j,hw] = BN(bias(1x1conv(osum, bal_w)))
// Block: 128-px tile, stages osum[64][128] once (32 KB). osum read ONCE total.
// Wave w: hw-half = w&1, oc-group og = w>>1 (og 0: j 0..8, og 1: j 9..17).
__global__ __launch_bounds__(256) void off_kernel(const float* __restrict__ osum,
    const float* __restrict__ balw, const float* __restrict__ balb,
    const float* __restrict__ s4, const float* __restrict__ g4,
    float* __restrict__ off)
{
    __shared__ float ls[CC * 128];   // 32 KB
    int bid = blockIdx.x;            // < 256
    int b   = bid >> 7;
    int hw0 = (bid & 127) * 128;

    const float* src = osum + (size_t)b * CHW + hw0;
    #pragma unroll
    for (int i = 0; i < 8; ++i) {
        int idx = threadIdx.x + i * 256;       // < 2048 float4
        int row = idx >> 5, col4 = idx & 31;
        ((float4*)ls)[row * 32 + col4] = *(const float4*)(src + (size_t)row * HWN + col4 * 4);
    }
    __syncthreads();

    int hw = (threadIdx.x & 63) + ((threadIdx.x >> 6) & 1) * 64;
    int og = __builtin_amdgcn_readfirstlane((int)(threadIdx.x >> 7));  // 0 or 1

    float acc[9];
    #pragma unroll
    for (int j = 0; j < 9; ++j) acc[j] = 0.f;
    for (int ic = 0; ic < CC; ++ic) {
        float v = ls[ic * 128 + hw];
        #pragma unroll
        for (int j = 0; j < 9; ++j)
            acc[j] += v * balw[(og * 9 + j) * CC + ic];   // wave-uniform -> s_load
    }
    #pragma unroll
    for (int j = 0; j < 9; ++j) {
        int oc = og * 9 + j;
        off[(size_t)b * (18 * HWN) + (size_t)oc * HWN + hw0 + hw] =
            (acc[j] + balb[oc]) * s4[oc] + g4[oc];
    }
}

// Stage 3: deformable gather, 2 channels/block, geometry shared.
// Grid: bid = (b*NBAND + band)*32 + cpair.  LDS: 2 plane-bands + tap weights.
__global__ __launch_bounds__(256, 4) void deform_kernel(
    const float* __restrict__ x,
    const float* __restrict__ off,
    const float* __restrict__ dw2, const float* __restrict__ dw3,
    const float* __restrict__ dw4, const float* __restrict__ dw5,
    float* __restrict__ pre)
{
    __shared__ float xs[CPB * PLANE];          // 34.8 KB
    __shared__ float wls[36 * CPB];            // [di*9+k][cc]

    int bid  = blockIdx.x;
    int cp   = bid & 31;
    int band = (bid >> 5) & (NBAND - 1);
    int b    = bid >> 9;
    int c0   = cp * CPB;
    int bc0  = b * CC + c0;

    int r_lo = band * BAND_H - HALO; if (r_lo < 0) r_lo = 0;
    int r_hi = band * BAND_H + BAND_H + HALO; if (r_hi > HH) r_hi = HH;
    int rows = r_hi - r_lo;
    int n4   = rows * (WW / 4);

    const float* xp0 = x + (size_t)bc0 * HWN;
    const float* xp1 = xp0 + HWN;

    for (int cc = 0; cc < CPB; ++cc) {
        const float4* src = (const float4*)(x + (size_t)(bc0 + cc) * HWN + r_lo * WW);
        float4* dst = (float4*)(xs + cc * PLANE);
        for (int i = threadIdx.x; i < n4; i += 256) dst[i] = src[i];
    }
    if (threadIdx.x < CPB) xs[threadIdx.x * PLANE + rows * WW] = 0.f;  // pad slot (x=128 read, weight 0)
    if (threadIdx.x < 36 * CPB) {
        int cc = threadIdx.x & 1, tap = threadIdx.x >> 1;
        int di = tap / 9, k = tap - di * 9;
        const float* dws = (di == 0) ? dw2 : (di == 1) ? dw3 : (di == 2) ? dw4 : dw5;
        wls[tap * CPB + cc] = dws[(c0 + cc) * 9 + k];
    }
    __syncthreads();

    const float* offb = off + (size_t)b * (18 * HWN);

    #pragma unroll 1
    for (int chunk = 0; chunk < 4; ++chunk) {
        int p = band * (BAND_H * WW) + chunk * 256 + threadIdx.x;
        int h = p >> 7;
        int w = p & (WW - 1);

        float oy[9], ox[9];
        #pragma unroll
        for (int k = 0; k < 9; ++k) {
            oy[k] = offb[((size_t)(2 * k) << 14) + p];
            ox[k] = offb[((size_t)(2 * k + 1) << 14) + p];
        }

        float acc0 = 0.f, acc1 = 0.f;
        #pragma unroll 1
        for (int di = 0; di < 4; ++di) {
            float d = (float)(di + 2);
            #pragma unroll
            for (int k = 0; k < 9; ++k) {
                float kyf = (float)(k / 3 - 1);
                float kxf = (float)(k % 3 - 1);
                float py = oy[k] + (float)h + d * kyf;
                float px = ox[k] + (float)w + d * kxf;
                float y0f = floorf(py), x0f = floorf(px);
                float wy = py - y0f, wx = px - x0f;
                int y0 = (int)y0f, x0 = (int)x0f;
                int y1 = y0 + 1, x1 = x0 + 1;
                bool yv0 = (y0 >= 0) && (y0 < HH);
                bool yv1 = (y1 >= 0) && (y1 < HH);
                bool xv0 = (x0 >= 0) && (x0 < WW);
                bool xv1 = (x1 >= 0) && (x1 < WW);
                // factored weights; OOB corners zeroed, single-valid-side redirected
                float cya = yv0 ? (1.f - wy) : (yv1 ? wy : 0.f);
                float cyb = (yv0 && yv1) ? wy : 0.f;
                float cxa = xv0 ? (1.f - wx) : (xv1 ? wx : 0.f);
                float cxb = (xv0 && xv1) ? wx : 0.f;
                int y0c = min(max(y0, 0), HH - 1);
                int y1c = min(max(y1, 0), HH - 1);
                int x0c = min(max(x0, 0), WW - 1);

                int r0 = y0c - r_lo, r1 = y1c - r_lo;
                float v00, v01, v10, v11, u00, u01, u10, u11;
                if (r0 >= 0 && y1c < r_hi) {               // fast path: LDS
                    int f0 = (r0 << 7) + x0c;              // float index
                    int f1 = (r1 << 7) + x0c;
                    v00 = xs[f0];         v01 = xs[f0 + 1];          // -> ds_read2
                    v10 = xs[f1];         v11 = xs[f1 + 1];
                    u00 = xs[PLANE + f0]; u01 = xs[PLANE + f0 + 1];
                    u10 = xs[PLANE + f1]; u11 = xs[PLANE + f1 + 1];
                } else {                                   // rare fallback
                    int xn = min(x0c + 1, WW - 1);
                    int i00 = y0c * WW + x0c, i01 = y0c * WW + xn;
                    int i10 = y1c * WW + x0c, i11 = y1c * WW + xn;
                    v00 = xp0[i00]; v01 = xp0[i01]; v10 = xp0[i10]; v11 = xp0[i11];
                    u00 = xp1[i00]; u01 = xp1[i01]; u10 = xp1[i10]; u11 = xp1[i11];
                }
                float2 wl = *(const float2*)&wls[(di * 9 + k) * CPB];
                float s0 = cya * (cxa * v00 + cxb * v01) + cyb * (cxa * v10 + cxb * v11);
                float s1 = cya * (cxa * u00 + cxb * u01) + cyb * (cxa * u10 + cxb * u11);
                acc0 += s0 * wl.x;
                acc1 += s1 * wl.y;
            }
        }
        pre[((size_t)bc0 << 14) + p]       = acc0;
        pre[((size_t)(bc0 + 1) << 14) + p] = acc1;
    }
}

// Stage 4 (LDS-tiled): out = (BN(bias(1x1conv(pre, fin_w)))) * x
// Block: 64-px tile, stages pre[64][64] once (16 KB). pre read ONCE total.
// Wave w handles oc in [w*16, w*16+16).
__global__ __launch_bounds__(256) void final_kernel(const float* __restrict__ pre,
    const float* __restrict__ finw, const float* __restrict__ finb,
    const float* __restrict__ s5, const float* __restrict__ g5,
    const float* __restrict__ x, float* __restrict__ out)
{
    __shared__ float ls[CC * 64];   // 16 KB
    int bid = blockIdx.x;           // < 512
    int b   = bid >> 8;
    int hw0 = (bid & 255) * 64;

    const float* src = pre + (size_t)b * CHW + hw0;
    #pragma unroll
    for (int i = 0; i < 4; ++i) {
        int idx = threadIdx.x + i * 256;      // < 1024 float4
        int row = idx >> 4, col4 = idx & 15;
        ((float4*)ls)[row * 16 + col4] = *(const float4*)(src + (size_t)row * HWN + col4 * 4);
    }
    __syncthreads();

    int hw = threadIdx.x & 63;
    int og = __builtin_amdgcn_readfirstlane((int)(threadIdx.x >> 6));  // 0..3

    float acc[16];
    #pragma unroll
    for (int j = 0; j < 16; ++j) acc[j] = 0.f;
    for (int ic = 0; ic < CC; ++ic) {
        float v = ls[ic * 64 + hw];
        #pragma unroll
        for (int j = 0; j < 16; ++j)
            acc[j] += v * finw[(og * 16 + j) * CC + ic];   // wave-uniform -> s_load
    }
    #pragma unroll
    for (int j = 0; j < 16; ++j) {
        int oc = og * 16 + j;
        size_t oidx = ((size_t)(b * CC + oc) << 14) + hw0 + hw;
        out[oidx] = ((acc[j] + finb[oc]) * s5[oc] + g5[oc]) * x[oidx];
    }
}

extern "C" void kernel_launch(void* const* d_in, const int* in_sizes, int n_in,
                              void* d_out, int out_size, void* d_ws, size_t ws_size,
                              hipStream_t stream) {
    const float* x      = (const float*)d_in[0];
    const float* off1_w = (const float*)d_in[1];
    const float* off1_b = (const float*)d_in[2];
    const float* bn1_s  = (const float*)d_in[3];
    const float* bn1_b  = (const float*)d_in[4];
    const float* off2_w = (const float*)d_in[5];
    const float* off2_b = (const float*)d_in[6];
    const float* bn2_s  = (const float*)d_in[7];
    const float* bn2_b  = (const float*)d_in[8];
    const float* off3_w = (const float*)d_in[9];
    const float* off3_b = (const float*)d_in[10];
    const float* bn3_s  = (const float*)d_in[11];
    const float* bn3_b  = (const float*)d_in[12];
    const float* bal_w  = (const float*)d_in[13];
    const float* bal_b  = (const float*)d_in[14];
    const float* bn4_s  = (const float*)d_in[15];
    const float* bn4_b  = (const float*)d_in[16];
    const float* dw2    = (const float*)d_in[17];
    const float* dw3    = (const float*)d_in[18];
    const float* dw4    = (const float*)d_in[19];
    const float* dw5    = (const float*)d_in[20];
    const float* fin_w  = (const float*)d_in[21];
    const float* fin_b  = (const float*)d_in[22];
    const float* bn5_s  = (const float*)d_in[23];
    const float* bn5_b  = (const float*)d_in[24];

    float* ws   = (float*)d_ws;
    float* osum = ws;                                  // 2,097,152 floats (8 MB)
    float* off  = ws + (size_t)BB * CHW;               //   589,824 floats (2.25 MB)
    float* pre  = off + (size_t)BB * 18 * HWN;         // 2,097,152 floats (8 MB)

    float* out = (float*)d_out;

    const int BLK = 256;
    osum_kernel<<<(BB * CHW) / BLK, BLK, 0, stream>>>(x,
        off1_w, off1_b, bn1_s, bn1_b,
        off2_w, off2_b, bn2_s, bn2_b,
        off3_w, off3_b, bn3_s, bn3_b, osum);
    off_kernel<<<BB * (HWN / 128), BLK, 0, stream>>>(osum, bal_w, bal_b, bn4_s, bn4_b, off);
    deform_kernel<<<BB * NBAND * (CC / CPB), BLK, 0, stream>>>(x, off, dw2, dw3, dw4, dw5, pre);
    final_kernel<<<BB * (HWN / 64), BLK, 0, stream>>>(pre, fin_w, fin_b, bn5_s, bn5_b, x, out);
}